// Round 1
// baseline (850.495 us; speedup 1.0000x reference)
//
#include <hip/hip_runtime.h>
#include <hip/hip_bf16.h>
#include <math.h>

#define B_ 4
#define L_ 2500
#define Y_ 8922
#define E_ 100
#define F_ 50
#define K_ 9

typedef __attribute__((ext_vector_type(8))) short bfrag8;   // 8 bf16 = 4 VGPR
typedef __attribute__((ext_vector_type(4))) float ffrag4;   // 4 fp32 acc

// ---- workspace layout ----
// floats 0..44999            : cwT (conv_w transposed [f][k][e]); REUSED as denom[B*Y]
//                              after k1 completes (zeroed via memset, filled by k2a atomics)
// ushort idx 90000..589999   : h bf16 [b][l][f]   (byte 180000, 16B-aligned)
// float idx 295000..2079399  : m [b][y][f] fp32 UNNORMALIZED partial sums (atomics)
// float idx 2079400..        : BCE partials
#define WS_CWT_F  0
#define WS_DEN_F  0
#define WS_HB_U16 90000
#define WS_M_F    295000
#define WS_PART_F 2079400
#define NBLK_FINAL 140

__device__ __forceinline__ void atomAddF(float* p, float v) {
    unsafeAtomicAdd(p, v);   // global_atomic_add_f32 (no CAS loop)
}

// ---------------- K0: transpose conv_w [F][E][K] -> cwT [F][K][E] ----------------
__global__ __launch_bounds__(256) void k0_cwt(const float* __restrict__ conv_w,
                                              float* __restrict__ cwT) {
    int idx = blockIdx.x * 256 + threadIdx.x;
    if (idx < F_ * E_ * K_) {
        int f = idx / (E_ * K_);
        int r = idx % (E_ * K_);
        int e = r / K_;
        int k = r % K_;
        cwT[f * (E_ * K_) + k * E_ + e] = conv_w[idx];
    }
}

// ---------------- K1: embedding + conv1d(same) + tanh -> h bf16 [b][l][f] ----------------
#define LT1 32
__global__ __launch_bounds__(256) void k1_embed_conv(
    const int* __restrict__ x, const float* __restrict__ emb_tab,
    const float* __restrict__ cwT, const float* __restrict__ conv_b,
    unsigned short* __restrict__ hb) {
    __shared__ __align__(16) float smem[(LT1 + 8) * E_];  // 40 rows x 100, 16 KB
    int b = blockIdx.y;
    int l0 = blockIdx.x * LT1;
    int tid = threadIdx.x;
    for (int idx = tid; idx < (LT1 + 8) * E_; idx += 256) {
        int r = idx / E_, e = idx % E_;
        int l = l0 + r - 4;
        float v = 0.f;
        if (l >= 0 && l < L_) {
            int tok = x[b * L_ + l];
            if (tok != 0) v = emb_tab[tok * E_ + e];
        }
        smem[idx] = v;
    }
    __syncthreads();
    const float4* s4 = (const float4*)smem;
    const float4* w4 = (const float4*)cwT;
    for (int idx = tid; idx < LT1 * F_; idx += 256) {
        int ll = idx / F_, f = idx % F_;
        int l = l0 + ll;
        if (l >= L_) continue;
        float acc = conv_b[f];
        for (int k = 0; k < K_; ++k) {
            const float4* se = s4 + (ll + k) * (E_ / 4);
            const float4* we = w4 + f * (E_ * K_ / 4) + k * (E_ / 4);
#pragma unroll
            for (int e4 = 0; e4 < E_ / 4; ++e4) {
                float4 a = se[e4];
                float4 w = we[e4];
                acc += a.x * w.x + a.y * w.y + a.z * w.z + a.w * w.w;
            }
        }
        __hip_bfloat16 hv = __float2bfloat16(tanhf(acc));
        hb[(size_t)(b * L_ + l) * F_ + f] = *reinterpret_cast<unsigned short*>(&hv);
    }
}

// ---------------- K2a: pass-1 (denominator + unnormalized m), L-split + atomics ----------------
// Grid: (NYB, CH1, B). Each block: 64 y's, 10 L-tiles of 64.
//   S = U.h^T (MFMA), P = exp(S) -> LDS, PV MFMA accumulates m and
//   (via ones-row at f=50 of h^T) the softmax denominator. Partials -> global atomics.
#define YT 64
#define LT 64
#define NLT ((L_ + LT - 1) / LT)   // 40
#define NYB ((Y_ + YT - 1) / YT)   // 140
#define HSTR 72                    // padded LDS leading dim (16B-aligned rows)
#define CH1 4
#define TPC1 (NLT / CH1)           // 10 tiles per chunk
__global__ __launch_bounds__(256) void k2a_denm(
    const float* __restrict__ Uw, const unsigned short* __restrict__ hb,
    float* __restrict__ mws, float* __restrict__ den) {
    __shared__ unsigned short hlf[64][HSTR];      // h tile [l][f]   9216 B
    __shared__ unsigned short hfl[64][HSTR];      // h tile [f][l] + ones row 50
    __shared__ unsigned short psh[4][16][HSTR];   // P per wave [y16][l64]

    int b = blockIdx.z;
    int y0 = blockIdx.x * YT;
    int ch = blockIdx.y;
    int tid = threadIdx.x;
    int wv = tid >> 6;
    int lane = tid & 63;
    int col = lane & 15;
    int quad = lane >> 4;
    int ywb = y0 + wv * 16;
    int ym = ywb + col;   // this lane's A-operand row (y)

    // U A-frags: A[m=lane&15][k=quad*8+j]
    bfrag8 uf[2];
#pragma unroll
    for (int kc = 0; kc < 2; ++kc) {
#pragma unroll
        for (int j = 0; j < 8; ++j) {
            int f = kc * 32 + quad * 8 + j;
            float v = (ym < Y_ && f < F_) ? Uw[(size_t)ym * F_ + f] : 0.f;
            __hip_bfloat16 bv = __float2bfloat16(v);
            uf[kc][j] = *reinterpret_cast<short*>(&bv);
        }
    }

    // one-time LDS pad init: hlf cols 50..63 = 0; hfl row 50 = 1.0, rows 51..63 = 0
    for (int i = tid; i < 64 * 14; i += 256) {
        int r = i / 14, c = 50 + (i % 14);
        hlf[r][c] = 0;
    }
    for (int i = tid; i < 14 * 64; i += 256) {
        int r = 50 + i / 64, c = i % 64;
        hfl[r][c] = (r == 50) ? (unsigned short)0x3F80 : (unsigned short)0;
    }

    ffrag4 macc[4];
#pragma unroll
    for (int nt = 0; nt < 4; ++nt) macc[nt] = (ffrag4){0.f, 0.f, 0.f, 0.f};

    const unsigned short* hbase = hb + (size_t)b * L_ * F_;

    for (int lt = ch * TPC1; lt < ch * TPC1 + TPC1; ++lt) {
        int l0 = lt * LT;
        __syncthreads();   // protect hlf/hfl/psh from previous iteration readers
        const unsigned int* src = (const unsigned int*)(hbase + (size_t)l0 * F_);
        for (int d = tid; d < LT * F_ / 2; d += 256) {   // 1600 dwords
            int r = d / 25, c = d % 25;
            unsigned int v = (l0 + r < L_) ? src[d] : 0u;
            *(unsigned int*)&hlf[r][2 * c] = v;
            hfl[2 * c][r] = (unsigned short)(v & 0xFFFF);
            hfl[2 * c + 1][r] = (unsigned short)(v >> 16);
        }
        __syncthreads();
        // S = U . h^T ; P = exp(S) masked, to LDS
#pragma unroll
        for (int nt = 0; nt < 4; ++nt) {
            ffrag4 s = (ffrag4){0.f, 0.f, 0.f, 0.f};
#pragma unroll
            for (int kc = 0; kc < 2; ++kc) {
                bfrag8 bf = *(const bfrag8*)&hlf[nt * 16 + col][kc * 32 + quad * 8];
                s = __builtin_amdgcn_mfma_f32_16x16x32_bf16(uf[kc], bf, s, 0, 0, 0);
            }
            int l = l0 + nt * 16 + col;
#pragma unroll
            for (int i = 0; i < 4; ++i) {
                float e = (l < L_) ? __expf(s[i]) : 0.f;
                __hip_bfloat16 be = __float2bfloat16(e);
                psh[wv][quad * 4 + i][nt * 16 + col] = *reinterpret_cast<unsigned short*>(&be);
            }
        }
        __syncthreads();   // P visible
        // m += P . h  (hfl row 50 of ones makes col 50 the denominator)
#pragma unroll
        for (int kc = 0; kc < 2; ++kc) {
            bfrag8 af = *(const bfrag8*)&psh[wv][col][kc * 32 + quad * 8];
#pragma unroll
            for (int nt = 0; nt < 4; ++nt) {
                bfrag8 bf = *(const bfrag8*)&hfl[nt * 16 + col][kc * 32 + quad * 8];
                macc[nt] = __builtin_amdgcn_mfma_f32_16x16x32_bf16(af, bf, macc[nt], 0, 0, 0);
            }
        }
    }

    // accumulate partials: C col = f (0..63), row = y. f==50 is the denominator.
#pragma unroll
    for (int nt = 0; nt < 4; ++nt) {
        int f = nt * 16 + col;
#pragma unroll
        for (int i = 0; i < 4; ++i) {
            int y = ywb + quad * 4 + i;
            if (y < Y_) {
                if (f < F_) {
                    atomAddF(&mws[((size_t)b * Y_ + y) * F_ + f], macc[nt][i]);
                } else if (f == F_) {
                    atomAddF(&den[(size_t)b * Y_ + y], macc[nt][i]);
                }
            }
        }
    }
}

// ---------------- K2b: alpha = exp(S)/denom, L-split for occupancy ----------------
// Grid: (NYB, CH2, B). Each block: 64 y's, 4 L-tiles of 64. Pure recompute + write.
#define CH2 10
#define TPC2 (NLT / CH2)   // 4 tiles per chunk
__global__ __launch_bounds__(256) void k2b_alpha(
    const float* __restrict__ Uw, const unsigned short* __restrict__ hb,
    const float* __restrict__ den, float* __restrict__ alpha) {
    __shared__ unsigned short hlf[64][HSTR];      // h tile [l][f]   9216 B

    int b = blockIdx.z;
    int y0 = blockIdx.x * YT;
    int ch = blockIdx.y;
    int tid = threadIdx.x;
    int wv = tid >> 6;
    int lane = tid & 63;
    int col = lane & 15;
    int quad = lane >> 4;
    int ywb = y0 + wv * 16;
    int ym = ywb + col;

    bfrag8 uf[2];
#pragma unroll
    for (int kc = 0; kc < 2; ++kc) {
#pragma unroll
        for (int j = 0; j < 8; ++j) {
            int f = kc * 32 + quad * 8 + j;
            float v = (ym < Y_ && f < F_) ? Uw[(size_t)ym * F_ + f] : 0.f;
            __hip_bfloat16 bv = __float2bfloat16(v);
            uf[kc][j] = *reinterpret_cast<short*>(&bv);
        }
    }

    // reciprocal denominators for this lane's 4 output rows
    float rd[4];
#pragma unroll
    for (int i = 0; i < 4; ++i) {
        int y = ywb + quad * 4 + i;
        rd[i] = (y < Y_) ? 1.0f / den[(size_t)b * Y_ + y] : 0.f;
    }

    // pad cols 50..63 = 0 (B-frag reads f up to 63)
    for (int i = tid; i < 64 * 14; i += 256) {
        int r = i / 14, c = 50 + (i % 14);
        hlf[r][c] = 0;
    }

    const unsigned short* hbase = hb + (size_t)b * L_ * F_;
    float* aout = alpha + (size_t)b * Y_ * L_;

    for (int lt = ch * TPC2; lt < ch * TPC2 + TPC2; ++lt) {
        int l0 = lt * LT;
        __syncthreads();
        const unsigned int* src = (const unsigned int*)(hbase + (size_t)l0 * F_);
        for (int d = tid; d < LT * F_ / 2; d += 256) {
            int r = d / 25, c = d % 25;
            unsigned int v = (l0 + r < L_) ? src[d] : 0u;
            *(unsigned int*)&hlf[r][2 * c] = v;
        }
        __syncthreads();
#pragma unroll
        for (int nt = 0; nt < 4; ++nt) {
            ffrag4 s = (ffrag4){0.f, 0.f, 0.f, 0.f};
#pragma unroll
            for (int kc = 0; kc < 2; ++kc) {
                bfrag8 bf = *(const bfrag8*)&hlf[nt * 16 + col][kc * 32 + quad * 8];
                s = __builtin_amdgcn_mfma_f32_16x16x32_bf16(uf[kc], bf, s, 0, 0, 0);
            }
            int l = l0 + nt * 16 + col;
            if (l < L_) {
#pragma unroll
                for (int i = 0; i < 4; ++i) {
                    int y = ywb + quad * 4 + i;
                    if (y < Y_) aout[(size_t)y * L_ + l] = __expf(s[i]) * rd[i];
                }
            }
        }
    }
}

// ---------------- K4: y = final_w . (m/den) + final_b ; yhat ; BCE partials ----------------
__global__ __launch_bounds__(256) void k4_final(
    const float* __restrict__ m, const float* __restrict__ den,
    const float* __restrict__ fw, const float* __restrict__ fb,
    const float* __restrict__ target, float* __restrict__ yhat,
    float* __restrict__ part) {
    int idx = blockIdx.x * 256 + threadIdx.x;
    float term = 0.f;
    if (idx < B_ * Y_) {
        int yy = idx % Y_;
        const float* mr = m + (size_t)idx * F_;
        const float* wr = fw + (size_t)yy * F_;
        float dot = 0.f;
#pragma unroll
        for (int f = 0; f < F_; ++f) dot += mr[f] * wr[f];
        float s = fb[yy] + dot / den[idx];
        yhat[idx] = 1.f / (1.f + __expf(-s));
        float t = target[idx];
        term = fmaxf(s, 0.f) - s * t + log1pf(__expf(-fabsf(s)));
    }
    float v = term;
    for (int off = 32; off > 0; off >>= 1) v += __shfl_down(v, off, 64);
    __shared__ float red[4];
    int lane = threadIdx.x & 63, w = threadIdx.x >> 6;
    if (lane == 0) red[w] = v;
    __syncthreads();
    if (threadIdx.x == 0) part[blockIdx.x] = red[0] + red[1] + red[2] + red[3];
}

// ---------------- K5: reduce partials -> loss ----------------
__global__ __launch_bounds__(256) void k5_loss(const float* __restrict__ part,
                                               float* __restrict__ loss_out) {
    float v = 0.f;
    for (int i = threadIdx.x; i < NBLK_FINAL; i += 256) v += part[i];
    for (int off = 32; off > 0; off >>= 1) v += __shfl_down(v, off, 64);
    __shared__ float red[4];
    int lane = threadIdx.x & 63, w = threadIdx.x >> 6;
    if (lane == 0) red[w] = v;
    __syncthreads();
    if (threadIdx.x == 0) loss_out[0] = (red[0] + red[1] + red[2] + red[3]) / (float)(B_ * Y_);
}

extern "C" void kernel_launch(void* const* d_in, const int* in_sizes, int n_in,
                              void* d_out, int out_size, void* d_ws, size_t ws_size,
                              hipStream_t stream) {
    const int*   x       = (const int*)d_in[0];
    const float* target  = (const float*)d_in[1];
    const float* emb_tab = (const float*)d_in[2];
    const float* conv_w  = (const float*)d_in[3];
    const float* conv_b  = (const float*)d_in[4];
    const float* U_w     = (const float*)d_in[5];
    const float* final_w = (const float*)d_in[6];
    const float* final_b = (const float*)d_in[7];

    float* out = (float*)d_out;
    float* wsf = (float*)d_ws;
    unsigned short* wsu = (unsigned short*)d_ws;

    float* cwT            = wsf + WS_CWT_F;
    float* den            = wsf + WS_DEN_F;   // aliases cwT; used only after k1
    unsigned short* hbf   = wsu + WS_HB_U16;
    float* mbuf           = wsf + WS_M_F;
    float* part           = wsf + WS_PART_F;

    float* yhat  = out;                    // [B*Y]
    float* loss  = out + (size_t)B_ * Y_;  // [1]
    float* alpha = loss + 1;               // [B*Y*L]

    k0_cwt<<<(F_ * E_ * K_ + 255) / 256, 256, 0, stream>>>(conv_w, cwT);
    k1_embed_conv<<<dim3((L_ + LT1 - 1) / LT1, B_), 256, 0, stream>>>(x, emb_tab, cwT, conv_b, hbf);
    // zero atomic accumulators (den aliases cwT, which is dead after k1)
    hipMemsetAsync(den, 0, (size_t)B_ * Y_ * sizeof(float), stream);
    hipMemsetAsync(mbuf, 0, (size_t)B_ * Y_ * F_ * sizeof(float), stream);
    k2a_denm<<<dim3(NYB, CH1, B_), 256, 0, stream>>>(U_w, hbf, mbuf, den);
    k2b_alpha<<<dim3(NYB, CH2, B_), 256, 0, stream>>>(U_w, hbf, den, alpha);
    k4_final<<<NBLK_FINAL, 256, 0, stream>>>(mbuf, den, final_w, final_b, target, yhat, part);
    k5_loss<<<1, 256, 0, stream>>>(part, loss);
}

// Round 2
// 832.132 us; speedup vs baseline: 1.0221x; 1.0221x over previous
//
#include <hip/hip_runtime.h>
#include <hip/hip_bf16.h>
#include <math.h>

#define B_ 4
#define L_ 2500
#define Y_ 8922
#define E_ 100
#define F_ 50
#define K_ 9

typedef __attribute__((ext_vector_type(8))) short bfrag8;   // 8 bf16 = 4 VGPR
typedef __attribute__((ext_vector_type(4))) float ffrag4;   // 4 fp32 acc

// ---- workspace layout (floats unless noted) ----
// 0..44999                    : cwT (conv_w transposed [f][k][e]); dead after k1
// ushort idx 90000..589999    : h bf16 [b][l][f]   (float idx 45000..294999)
// 295000..7432599             : mp  [CH1][b][y][f] per-chunk partial m (no atomics)
// 7432600..7575351            : denp[CH1][b][y]    per-chunk partial denom
// 7575352..                   : BCE partials
#define WS_CWT_F  0
#define WS_HB_U16 90000
#define WS_MP_F   295000
#define BYF_      (B_ * Y_ * F_)        /* 1,784,400 */
#define BY_       (B_ * Y_)             /* 35,688 */
#define WS_DENP_F (WS_MP_F + 4 * BYF_)  /* 7,432,600 */
#define WS_PART_F (WS_DENP_F + 4 * BY_) /* 7,575,352 */
#define NBLK_FINAL 140

// ---------------- K0: transpose conv_w [F][E][K] -> cwT [F][K][E] ----------------
__global__ __launch_bounds__(256) void k0_cwt(const float* __restrict__ conv_w,
                                              float* __restrict__ cwT) {
    int idx = blockIdx.x * 256 + threadIdx.x;
    if (idx < F_ * E_ * K_) {
        int f = idx / (E_ * K_);
        int r = idx % (E_ * K_);
        int e = r / K_;
        int k = r % K_;
        cwT[f * (E_ * K_) + k * E_ + e] = conv_w[idx];
    }
}

// ---------------- K1: embedding + conv1d(same) + tanh -> h bf16 [b][l][f] ----------------
#define LT1 32
__global__ __launch_bounds__(256) void k1_embed_conv(
    const int* __restrict__ x, const float* __restrict__ emb_tab,
    const float* __restrict__ cwT, const float* __restrict__ conv_b,
    unsigned short* __restrict__ hb) {
    __shared__ __align__(16) float smem[(LT1 + 8) * E_];  // 40 rows x 100, 16 KB
    int b = blockIdx.y;
    int l0 = blockIdx.x * LT1;
    int tid = threadIdx.x;
    for (int idx = tid; idx < (LT1 + 8) * E_; idx += 256) {
        int r = idx / E_, e = idx % E_;
        int l = l0 + r - 4;
        float v = 0.f;
        if (l >= 0 && l < L_) {
            int tok = x[b * L_ + l];
            if (tok != 0) v = emb_tab[tok * E_ + e];
        }
        smem[idx] = v;
    }
    __syncthreads();
    const float4* s4 = (const float4*)smem;
    const float4* w4 = (const float4*)cwT;
    for (int idx = tid; idx < LT1 * F_; idx += 256) {
        int ll = idx / F_, f = idx % F_;
        int l = l0 + ll;
        if (l >= L_) continue;
        float acc = conv_b[f];
        for (int k = 0; k < K_; ++k) {
            const float4* se = s4 + (ll + k) * (E_ / 4);
            const float4* we = w4 + f * (E_ * K_ / 4) + k * (E_ / 4);
#pragma unroll
            for (int e4 = 0; e4 < E_ / 4; ++e4) {
                float4 a = se[e4];
                float4 w = we[e4];
                acc += a.x * w.x + a.y * w.y + a.z * w.z + a.w * w.w;
            }
        }
        __hip_bfloat16 hv = __float2bfloat16(tanhf(acc));
        hb[(size_t)(b * L_ + l) * F_ + f] = *reinterpret_cast<unsigned short*>(&hv);
    }
}

// ---------------- K2a: pass-1 (denominator + unnormalized m), L-split, chunk partials ----------------
// Grid: (NYB, CH1, B). Each block: 64 y's, 10 L-tiles of 64.
//   S = U.h^T (MFMA), P = exp(S) -> LDS, PV MFMA accumulates m and
//   (via ones-row at f=50 of h^T) the softmax denominator. Plain stores to per-chunk buffers.
#define YT 64
#define LT 64
#define NLT ((L_ + LT - 1) / LT)   // 40
#define NYB ((Y_ + YT - 1) / YT)   // 140
#define HSTR 72                    // padded LDS leading dim (16B-aligned rows)
#define CH1 4
#define TPC1 (NLT / CH1)           // 10 tiles per chunk
__global__ __launch_bounds__(256) void k2a_denm(
    const float* __restrict__ Uw, const unsigned short* __restrict__ hb,
    float* __restrict__ mp, float* __restrict__ denp) {
    __shared__ unsigned short hlf[64][HSTR];      // h tile [l][f]   9216 B
    __shared__ unsigned short hfl[64][HSTR];      // h tile [f][l] + ones row 50
    __shared__ unsigned short psh[4][16][HSTR];   // P per wave [y16][l64]

    int b = blockIdx.z;
    int y0 = blockIdx.x * YT;
    int ch = blockIdx.y;
    int tid = threadIdx.x;
    int wv = tid >> 6;
    int lane = tid & 63;
    int col = lane & 15;
    int quad = lane >> 4;
    int ywb = y0 + wv * 16;
    int ym = ywb + col;   // this lane's A-operand row (y)

    // U A-frags: A[m=lane&15][k=quad*8+j]
    bfrag8 uf[2];
#pragma unroll
    for (int kc = 0; kc < 2; ++kc) {
#pragma unroll
        for (int j = 0; j < 8; ++j) {
            int f = kc * 32 + quad * 8 + j;
            float v = (ym < Y_ && f < F_) ? Uw[(size_t)ym * F_ + f] : 0.f;
            __hip_bfloat16 bv = __float2bfloat16(v);
            uf[kc][j] = *reinterpret_cast<short*>(&bv);
        }
    }

    // one-time LDS pad init: hlf cols 50..63 = 0; hfl row 50 = 1.0, rows 51..63 = 0
    for (int i = tid; i < 64 * 14; i += 256) {
        int r = i / 14, c = 50 + (i % 14);
        hlf[r][c] = 0;
    }
    for (int i = tid; i < 14 * 64; i += 256) {
        int r = 50 + i / 64, c = i % 64;
        hfl[r][c] = (r == 50) ? (unsigned short)0x3F80 : (unsigned short)0;
    }

    ffrag4 macc[4];
#pragma unroll
    for (int nt = 0; nt < 4; ++nt) macc[nt] = (ffrag4){0.f, 0.f, 0.f, 0.f};

    const unsigned short* hbase = hb + (size_t)b * L_ * F_;

    for (int lt = ch * TPC1; lt < ch * TPC1 + TPC1; ++lt) {
        int l0 = lt * LT;
        __syncthreads();   // protect hlf/hfl/psh from previous iteration readers
        const unsigned int* src = (const unsigned int*)(hbase + (size_t)l0 * F_);
        for (int d = tid; d < LT * F_ / 2; d += 256) {   // 1600 dwords
            int r = d / 25, c = d % 25;
            unsigned int v = (l0 + r < L_) ? src[d] : 0u;
            *(unsigned int*)&hlf[r][2 * c] = v;
            hfl[2 * c][r] = (unsigned short)(v & 0xFFFF);
            hfl[2 * c + 1][r] = (unsigned short)(v >> 16);
        }
        __syncthreads();
        // S = U . h^T ; P = exp(S) masked, to LDS
#pragma unroll
        for (int nt = 0; nt < 4; ++nt) {
            ffrag4 s = (ffrag4){0.f, 0.f, 0.f, 0.f};
#pragma unroll
            for (int kc = 0; kc < 2; ++kc) {
                bfrag8 bf = *(const bfrag8*)&hlf[nt * 16 + col][kc * 32 + quad * 8];
                s = __builtin_amdgcn_mfma_f32_16x16x32_bf16(uf[kc], bf, s, 0, 0, 0);
            }
            int l = l0 + nt * 16 + col;
#pragma unroll
            for (int i = 0; i < 4; ++i) {
                float e = (l < L_) ? __expf(s[i]) : 0.f;
                __hip_bfloat16 be = __float2bfloat16(e);
                psh[wv][quad * 4 + i][nt * 16 + col] = *reinterpret_cast<unsigned short*>(&be);
            }
        }
        __syncthreads();   // P visible
        // m += P . h  (hfl row 50 of ones makes col 50 the denominator)
#pragma unroll
        for (int kc = 0; kc < 2; ++kc) {
            bfrag8 af = *(const bfrag8*)&psh[wv][col][kc * 32 + quad * 8];
#pragma unroll
            for (int nt = 0; nt < 4; ++nt) {
                bfrag8 bf = *(const bfrag8*)&hfl[nt * 16 + col][kc * 32 + quad * 8];
                macc[nt] = __builtin_amdgcn_mfma_f32_16x16x32_bf16(af, bf, macc[nt], 0, 0, 0);
            }
        }
    }

    // plain stores of chunk partials: C col = f (0..63), row = y. f==50 is the denominator.
    float* mchunk = mp + (size_t)ch * BYF_;
#pragma unroll
    for (int nt = 0; nt < 4; ++nt) {
        int f = nt * 16 + col;
#pragma unroll
        for (int i = 0; i < 4; ++i) {
            int y = ywb + quad * 4 + i;
            if (y < Y_) {
                if (f < F_) {
                    mchunk[((size_t)b * Y_ + y) * F_ + f] = macc[nt][i];
                } else if (f == F_) {
                    denp[(size_t)ch * BY_ + b * Y_ + y] = macc[nt][i];
                }
            }
        }
    }
}

// ---------------- K2b: alpha = exp(S)/denom, LDS-staged 256B-contiguous stores ----------------
// Grid: (NYB, CH2, B). Each block: 64 y's, 4 L-tiles of 64.
#define CH2 10
#define TPC2 (NLT / CH2)   // 4 tiles per chunk
__global__ __launch_bounds__(256) void k2b_alpha(
    const float* __restrict__ Uw, const unsigned short* __restrict__ hb,
    const float* __restrict__ denp, float* __restrict__ alpha) {
    __shared__ unsigned short hlf[64][HSTR];   // h tile [l][f]   9216 B
    __shared__ float alf[64][68];              // alpha tile [y][l], padded  17408 B

    int b = blockIdx.z;
    int y0 = blockIdx.x * YT;
    int ch = blockIdx.y;
    int tid = threadIdx.x;
    int wv = tid >> 6;
    int lane = tid & 63;
    int col = lane & 15;
    int quad = lane >> 4;
    int ywb = y0 + wv * 16;
    int ym = ywb + col;

    bfrag8 uf[2];
#pragma unroll
    for (int kc = 0; kc < 2; ++kc) {
#pragma unroll
        for (int j = 0; j < 8; ++j) {
            int f = kc * 32 + quad * 8 + j;
            float v = (ym < Y_ && f < F_) ? Uw[(size_t)ym * F_ + f] : 0.f;
            __hip_bfloat16 bv = __float2bfloat16(v);
            uf[kc][j] = *reinterpret_cast<short*>(&bv);
        }
    }

    // reciprocal denominators for this lane's 4 output rows (sum the 4 chunk partials)
    float rd[4];
#pragma unroll
    for (int i = 0; i < 4; ++i) {
        int y = ywb + quad * 4 + i;
        float d = 0.f;
        if (y < Y_) {
#pragma unroll
            for (int c = 0; c < CH1; ++c) d += denp[(size_t)c * BY_ + b * Y_ + y];
            rd[i] = 1.0f / d;
        } else {
            rd[i] = 0.f;
        }
    }

    // pad cols 50..63 = 0 (B-frag reads f up to 63; stale LDS could be NaN)
    for (int i = tid; i < 64 * 14; i += 256) {
        int r = i / 14, c = 50 + (i % 14);
        hlf[r][c] = 0;
    }

    const unsigned short* hbase = hb + (size_t)b * L_ * F_;
    float* aout = alpha + (size_t)b * Y_ * L_;

    for (int lt = ch * TPC2; lt < ch * TPC2 + TPC2; ++lt) {
        int l0 = lt * LT;
        __syncthreads();   // prev iteration's alf reads + hlf reads done
        const unsigned int* src = (const unsigned int*)(hbase + (size_t)l0 * F_);
        for (int d = tid; d < LT * F_ / 2; d += 256) {
            int r = d / 25, c = d % 25;
            unsigned int v = (l0 + r < L_) ? src[d] : 0u;
            *(unsigned int*)&hlf[r][2 * c] = v;
        }
        __syncthreads();
#pragma unroll
        for (int nt = 0; nt < 4; ++nt) {
            ffrag4 s = (ffrag4){0.f, 0.f, 0.f, 0.f};
#pragma unroll
            for (int kc = 0; kc < 2; ++kc) {
                bfrag8 bf = *(const bfrag8*)&hlf[nt * 16 + col][kc * 32 + quad * 8];
                s = __builtin_amdgcn_mfma_f32_16x16x32_bf16(uf[kc], bf, s, 0, 0, 0);
            }
            int l = l0 + nt * 16 + col;
#pragma unroll
            for (int i = 0; i < 4; ++i) {
                float v = (l < L_) ? __expf(s[i]) * rd[i] : 0.f;
                alf[wv * 16 + quad * 4 + i][nt * 16 + col] = v;
            }
        }
        __syncthreads();   // alf tile complete
        int lrem = L_ - l0;
        if (lrem >= LT) {
            // 16 lanes x float4 = 256 B contiguous per y-row (16B-aligned: L*4 and l0*4 are)
            for (int i4 = tid; i4 < 64 * 16; i4 += 256) {
                int r = i4 >> 4, c4 = i4 & 15;
                int y = y0 + r;
                if (y < Y_) {
                    float4 v = *(const float4*)&alf[r][c4 * 4];
                    *(float4*)&aout[(size_t)y * L_ + l0 + c4 * 4] = v;
                }
            }
        } else {
            for (int i = tid; i < 64 * LT; i += 256) {
                int r = i >> 6, c = i & 63;
                int y = y0 + r, l = l0 + c;
                if (y < Y_ && l < L_) aout[(size_t)y * L_ + l] = alf[r][c];
            }
        }
    }
}

// ---------------- K4: y = final_w . (sum_ch m / sum_ch den) + final_b ; yhat ; BCE ----------------
__global__ __launch_bounds__(256) void k4_final(
    const float* __restrict__ mp, const float* __restrict__ denp,
    const float* __restrict__ fw, const float* __restrict__ fb,
    const float* __restrict__ target, float* __restrict__ yhat,
    float* __restrict__ part) {
    int idx = blockIdx.x * 256 + threadIdx.x;
    float term = 0.f;
    if (idx < B_ * Y_) {
        int yy = idx % Y_;
        const float* wr = fw + (size_t)yy * F_;
        float dot = 0.f;
        float den = 0.f;
#pragma unroll
        for (int c = 0; c < CH1; ++c) {
            den += denp[(size_t)c * BY_ + idx];
            const float* mr = mp + (size_t)c * BYF_ + (size_t)idx * F_;
#pragma unroll
            for (int f = 0; f < F_; ++f) dot += mr[f] * wr[f];
        }
        float s = fb[yy] + dot / den;
        yhat[idx] = 1.f / (1.f + __expf(-s));
        float t = target[idx];
        term = fmaxf(s, 0.f) - s * t + log1pf(__expf(-fabsf(s)));
    }
    float v = term;
    for (int off = 32; off > 0; off >>= 1) v += __shfl_down(v, off, 64);
    __shared__ float red[4];
    int lane = threadIdx.x & 63, w = threadIdx.x >> 6;
    if (lane == 0) red[w] = v;
    __syncthreads();
    if (threadIdx.x == 0) part[blockIdx.x] = red[0] + red[1] + red[2] + red[3];
}

// ---------------- K5: reduce partials -> loss ----------------
__global__ __launch_bounds__(256) void k5_loss(const float* __restrict__ part,
                                               float* __restrict__ loss_out) {
    float v = 0.f;
    for (int i = threadIdx.x; i < NBLK_FINAL; i += 256) v += part[i];
    for (int off = 32; off > 0; off >>= 1) v += __shfl_down(v, off, 64);
    __shared__ float red[4];
    int lane = threadIdx.x & 63, w = threadIdx.x >> 6;
    if (lane == 0) red[w] = v;
    __syncthreads();
    if (threadIdx.x == 0) loss_out[0] = (red[0] + red[1] + red[2] + red[3]) / (float)(B_ * Y_);
}

extern "C" void kernel_launch(void* const* d_in, const int* in_sizes, int n_in,
                              void* d_out, int out_size, void* d_ws, size_t ws_size,
                              hipStream_t stream) {
    const int*   x       = (const int*)d_in[0];
    const float* target  = (const float*)d_in[1];
    const float* emb_tab = (const float*)d_in[2];
    const float* conv_w  = (const float*)d_in[3];
    const float* conv_b  = (const float*)d_in[4];
    const float* U_w     = (const float*)d_in[5];
    const float* final_w = (const float*)d_in[6];
    const float* final_b = (const float*)d_in[7];

    float* out = (float*)d_out;
    float* wsf = (float*)d_ws;
    unsigned short* wsu = (unsigned short*)d_ws;

    float* cwT            = wsf + WS_CWT_F;
    unsigned short* hbf   = wsu + WS_HB_U16;
    float* mpart          = wsf + WS_MP_F;
    float* denp           = wsf + WS_DENP_F;
    float* part           = wsf + WS_PART_F;

    float* yhat  = out;                    // [B*Y]
    float* loss  = out + (size_t)B_ * Y_;  // [1]
    float* alpha = loss + 1;               // [B*Y*L]

    k0_cwt<<<(F_ * E_ * K_ + 255) / 256, 256, 0, stream>>>(conv_w, cwT);
    k1_embed_conv<<<dim3((L_ + LT1 - 1) / LT1, B_), 256, 0, stream>>>(x, emb_tab, cwT, conv_b, hbf);
    k2a_denm<<<dim3(NYB, CH1, B_), 256, 0, stream>>>(U_w, hbf, mpart, denp);
    k2b_alpha<<<dim3(NYB, CH2, B_), 256, 0, stream>>>(U_w, hbf, denp, alpha);
    k4_final<<<NBLK_FINAL, 256, 0, stream>>>(mpart, denp, final_w, final_b, target, yhat, part);
    k5_loss<<<1, 256, 0, stream>>>(part, loss);
}